// Round 6
// baseline (528.661 us; speedup 1.0000x reference)
//
#include <hip/hip_runtime.h>
#include <math.h>
#include <type_traits>

typedef __bf16 bf16;
typedef __attribute__((ext_vector_type(8))) __bf16 bf16x8;
typedef __attribute__((ext_vector_type(4))) float f32x4;

#define SEQ 2048
#define DM 1024
#define NH 16
#define HD 64
#define BATCH 4

#define NEG_BIG (-1e30f)
// softmax in exp2 domain: p = 2^(s * (1/8) * log2(e))
#define SCALE_L2E 0.18033688011f

__device__ inline bf16x8 cvt_f32x8(const float* p) {
  f32x4 x0 = *(const f32x4*)p;
  f32x4 x1 = *(const f32x4*)(p + 4);
  bf16x8 r;
  r[0] = (bf16)x0[0]; r[1] = (bf16)x0[1]; r[2] = (bf16)x0[2]; r[3] = (bf16)x0[3];
  r[4] = (bf16)x1[0]; r[5] = (bf16)x1[1]; r[6] = (bf16)x1[2]; r[7] = (bf16)x1[3];
  return r;
}

// async global->LDS DMA, 16 B per lane; lptr is wave-uniform base, HW writes
// lane i at lptr + i*16 (m97 pattern).
__device__ inline void async_copy16(const bf16* g, bf16* l) {
  __builtin_amdgcn_global_load_lds(
      (const __attribute__((address_space(1))) unsigned int*)g,
      (__attribute__((address_space(3))) unsigned int*)l, 16, 0, 0);
}

// ---------------------------------------------------------------------------
// f32 -> bf16 elementwise convert (memory-bound pre-pass), 8 elems/thread.
// ---------------------------------------------------------------------------
__global__ __launch_bounds__(256) void cvt_kernel(const float* __restrict__ src,
                                                  bf16* __restrict__ dst) {
  size_t i = ((size_t)blockIdx.x * 256 + threadIdx.x) * 8;
  *(bf16x8*)(dst + i) = cvt_f32x8(src + i);
}

// ---------------------------------------------------------------------------
// Weight transpose + f32->bf16 convert: Wt[n][k] = (bf16)W[k][n], 1024x1024.
// ---------------------------------------------------------------------------
__global__ __launch_bounds__(256) void transpose_w_kernel(
    const float* __restrict__ Wq, const float* __restrict__ Wk,
    const float* __restrict__ Wv, const float* __restrict__ Wo,
    bf16* __restrict__ Tq, bf16* __restrict__ Tk,
    bf16* __restrict__ Tv, bf16* __restrict__ To) {
  __shared__ bf16 tile[64 * 66];
  int z = blockIdx.z;
  const float* src = (z == 0) ? Wq : (z == 1) ? Wk : (z == 2) ? Wv : Wo;
  bf16* dst = (z == 0) ? Tq : (z == 1) ? Tk : (z == 2) ? Tv : To;
  int n0 = blockIdx.x * 64, k0 = blockIdx.y * 64;
  int t = threadIdx.x;
  int c = t & 63, rr = t >> 6;
#pragma unroll
  for (int i = 0; i < 16; i++) {
    int k = i * 4 + rr;
    tile[k * 66 + c] = (bf16)src[(size_t)(k0 + k) * DM + n0 + c];
  }
  __syncthreads();
#pragma unroll
  for (int i = 0; i < 16; i++) {
    int n = i * 4 + rr;
    dst[(size_t)(n0 + n) * DM + k0 + c] = tile[c * 66 + n];
  }
}

// ---------------------------------------------------------------------------
// V transpose (bf16 -> bf16): Vn[b,s,h*64+d] -> Vt[((b*16+h)*64+d)*2048 + s]
// ---------------------------------------------------------------------------
__global__ __launch_bounds__(256) void transpose_v_kernel(
    const bf16* __restrict__ Vn, bf16* __restrict__ Vt) {
  __shared__ bf16 tile[64 * 66];
  int s0 = blockIdx.x * 64;
  int h = blockIdx.y, b = blockIdx.z;
  int t = threadIdx.x;
  int c = t & 63, rr = t >> 6;
#pragma unroll
  for (int i = 0; i < 16; i++) {
    int s = i * 4 + rr;
    tile[s * 66 + c] = Vn[((size_t)(b * SEQ + s0 + s)) * DM + h * HD + c];
  }
  __syncthreads();
#pragma unroll
  for (int i = 0; i < 16; i++) {
    int d = i * 4 + rr;
    Vt[((size_t)(b * NH + h) * HD + d) * SEQ + s0 + c] = tile[c * 66 + d];
  }
}

// ---------------------------------------------------------------------------
// GEMM + bias, m97-style (unchanged from round 5).
// ---------------------------------------------------------------------------
template <typename CT>
__global__ __launch_bounds__(256) void gemm_bias_kernel(
    const bf16* __restrict__ A, const bf16* __restrict__ Bt,
    const float* __restrict__ bias, CT* __restrict__ C) {
  __shared__ bf16 As[128 * 32];
  __shared__ bf16 Bs[128 * 32];
  int m0 = blockIdx.x * 128, n0 = blockIdx.y * 128;
  int t = threadIdx.x;
  int wave = t >> 6, lane = t & 63, lr = lane & 15, lq = lane >> 4;
  int wm = (wave & 1) * 64, wn = (wave >> 1) * 64;

  f32x4 acc[4][4];
#pragma unroll
  for (int i = 0; i < 4; i++)
#pragma unroll
    for (int j = 0; j < 4; j++) acc[i][j] = (f32x4){0.f, 0.f, 0.f, 0.f};

  int srow = wave * 32 + (lane >> 2);
  int skc = lane & 3;
  const bf16* gA0 = A + (size_t)(m0 + srow) * DM + skc * 8;
  const bf16* gA1 = gA0 + (size_t)16 * DM;
  const bf16* gB0 = Bt + (size_t)(n0 + srow) * DM + skc * 8;
  const bf16* gB1 = gB0 + (size_t)16 * DM;
  bf16* lA0 = &As[(wave * 128) * 8];
  bf16* lA1 = &As[(wave * 128 + 64) * 8];
  bf16* lB0 = &Bs[(wave * 128) * 8];
  bf16* lB1 = &Bs[(wave * 128 + 64) * 8];

  for (int k0 = 0; k0 < DM; k0 += 32) {
    async_copy16(gA0, lA0);
    async_copy16(gA1, lA1);
    async_copy16(gB0, lB0);
    async_copy16(gB1, lB1);
    gA0 += 32; gA1 += 32; gB0 += 32; gB1 += 32;
    __syncthreads();

    bf16x8 af[4], bfr[4];
#pragma unroll
    for (int i = 0; i < 4; i++)
      af[i] = *(const bf16x8*)&As[(wm + i * 16 + lr) * 32 + lq * 8];
#pragma unroll
    for (int j = 0; j < 4; j++)
      bfr[j] = *(const bf16x8*)&Bs[(wn + j * 16 + lr) * 32 + lq * 8];
#pragma unroll
    for (int i = 0; i < 4; i++)
#pragma unroll
      for (int j = 0; j < 4; j++)
        acc[i][j] = __builtin_amdgcn_mfma_f32_16x16x32_bf16(af[i], bfr[j],
                                                            acc[i][j], 0, 0, 0);
    __syncthreads();
  }

#pragma unroll
  for (int j = 0; j < 4; j++) {
    int col = n0 + wn + j * 16 + lr;
    float bv = bias[col];
#pragma unroll
    for (int i = 0; i < 4; i++) {
      int row = m0 + wm + i * 16 + lq * 4;
#pragma unroll
      for (int r = 0; r < 4; r++) {
        C[(size_t)(row + r) * DM + col] = (CT)(acc[i][j][r] + bv);
      }
    }
  }
}

// ---------------------------------------------------------------------------
// Flash attention v3 (causal): zero LDS, zero barriers, wave-independent.
//
// v3 change: q-tile shrinks 32 -> 16 rows. Each wave owns the complementary
// pair (p, 127-p), p in [0,64) -> 4096 waves = 4 waves/SIMD (was 2), each
// wave exactly 33 kv64-tiles. Total MFMA unchanged; per-tile VALU halves;
// 2x latency hiding. __launch_bounds__(256,4) pins VGPR <= 128.
// ---------------------------------------------------------------------------
__global__ __launch_bounds__(256, 4) void attention_kernel(
    const bf16* __restrict__ Q, const bf16* __restrict__ K,
    const bf16* __restrict__ Vt, bf16* __restrict__ ctx) {
  int h = blockIdx.y, b = blockIdx.z;
  int t = threadIdx.x, wave = t >> 6, lane = t & 63, lr = lane & 15,
      lq = lane >> 4;
  int p = blockIdx.x * 4 + wave;  // pair index in [0,64)

  const bf16* Qb = Q + (size_t)b * SEQ * DM + h * HD;
  const bf16* Kb = K + (size_t)b * SEQ * DM + h * HD;
  const bf16* Vb = Vt + (size_t)(b * NH + h) * HD * SEQ;
  bf16* Cb = ctx + (size_t)b * SEQ * DM + h * HD;

#pragma unroll 1
  for (int pass = 0; pass < 2; pass++) {
    int tq = pass ? (127 - p) : p;  // 16-row q-tile index
    int q0 = tq * 16;

    // Q fragment (B-operand): B[n=q][k=d], n = lr, k = ks*32 + lq*8 + j
    bf16x8 qf[2];
#pragma unroll
    for (int ks = 0; ks < 2; ks++)
      qf[ks] = *(const bf16x8*)&Qb[(size_t)(q0 + lr) * DM + ks * 32 + lq * 8];

    f32x4 o[4];  // O[dj(d)], C-layout: col=d=lr, row=q=lq*4+r
    float m_st = NEG_BIG, l_st = 0.f;
#pragma unroll
    for (int dj = 0; dj < 4; dj++) o[dj] = (f32x4){0.f, 0.f, 0.f, 0.f};

    int kv_end = q0 + 16;
#pragma unroll 1
    for (int kv0 = 0; kv0 < kv_end; kv0 += 64) {
      // --- stage K and V fragments from global (16B/lane each) ---
      bf16x8 kf[4][2];  // A[m=kv][k=d]: m = lr, k = ks*32 + lq*8 + j
#pragma unroll
      for (int kvt = 0; kvt < 4; kvt++)
#pragma unroll
        for (int ks = 0; ks < 2; ks++)
          kf[kvt][ks] = *(const bf16x8*)&Kb[(size_t)(kv0 + kvt * 16 + lr) * DM +
                                            ks * 32 + lq * 8];
      bf16x8 vf[4][2];  // B[n=d][k=kv]: n = lr, k = ks2*32 + lq*8 + j
#pragma unroll
      for (int dj = 0; dj < 4; dj++)
#pragma unroll
        for (int ks2 = 0; ks2 < 2; ks2++)
          vf[dj][ks2] = *(const bf16x8*)&Vb[(size_t)(dj * 16 + lr) * SEQ + kv0 +
                                            ks2 * 32 + lq * 8];

      // --- S^T = K Q^T : row = kv = kvt*16 + lq*4 + r, col = q = lr ---
      f32x4 s[4];
#pragma unroll
      for (int kvt = 0; kvt < 4; kvt++) {
        f32x4 acc = (f32x4){0.f, 0.f, 0.f, 0.f};
        acc = __builtin_amdgcn_mfma_f32_16x16x32_bf16(kf[kvt][0], qf[0], acc,
                                                      0, 0, 0);
        acc = __builtin_amdgcn_mfma_f32_16x16x32_bf16(kf[kvt][1], qf[1], acc,
                                                      0, 0, 0);
        s[kvt] = acc;
      }

      // --- scale into exp2 domain + causal mask (only near diagonal) ---
      if (kv0 + 63 > q0) {
#pragma unroll
        for (int kvt = 0; kvt < 4; kvt++)
#pragma unroll
          for (int r = 0; r < 4; r++) {
            int kv_g = kv0 + kvt * 16 + lq * 4 + r;
            int q_g = q0 + lr;
            float v = s[kvt][r] * SCALE_L2E;
            s[kvt][r] = (kv_g > q_g) ? NEG_BIG : v;
          }
      } else {
#pragma unroll
        for (int kvt = 0; kvt < 4; kvt++)
#pragma unroll
          for (int r = 0; r < 4; r++) s[kvt][r] *= SCALE_L2E;
      }

      // --- online softmax (per q = lane column) ---
      float mx = s[0][0];
#pragma unroll
      for (int kvt = 0; kvt < 4; kvt++)
#pragma unroll
        for (int r = 0; r < 4; r++) mx = fmaxf(mx, s[kvt][r]);
      mx = fmaxf(mx, __shfl_xor(mx, 16));
      mx = fmaxf(mx, __shfl_xor(mx, 32));
      float mnew = fmaxf(m_st, mx);
      float alpha = exp2f(m_st - mnew);
      m_st = mnew;
      float rs = 0.f;
#pragma unroll
      for (int kvt = 0; kvt < 4; kvt++)
#pragma unroll
        for (int r = 0; r < 4; r++) {
          float pv = exp2f(s[kvt][r] - mnew);
          s[kvt][r] = pv;
          rs += pv;
        }
      rs += __shfl_xor(rs, 16);
      rs += __shfl_xor(rs, 32);
      l_st = l_st * alpha + rs;

      // --- alpha transpose (q on S-columns -> q on O-rows) + rescale O ---
      float aT[4];
#pragma unroll
      for (int r = 0; r < 4; r++) aT[r] = __shfl(alpha, lq * 4 + r);
#pragma unroll
      for (int dj = 0; dj < 4; dj++)
#pragma unroll
        for (int r = 0; r < 4; r++) o[dj][r] *= aT[r];

      // --- P (C-layout) -> A-operand fragment via shuffles, then O += P V ---
      int src_base = (lq & 1) * 32 + lr;
      bool hi = (lq >> 1) != 0;
#pragma unroll
      for (int ks2 = 0; ks2 < 2; ks2++) {
        bf16x8 pf;
#pragma unroll
        for (int j = 0; j < 8; j++) {
          int src = src_base + (j >> 2) * 16;
          float v0 = __shfl(s[2 * ks2][j & 3], src);
          float v1 = __shfl(s[2 * ks2 + 1][j & 3], src);
          pf[j] = (bf16)(hi ? v1 : v0);
        }
#pragma unroll
        for (int dj = 0; dj < 4; dj++)
          o[dj] = __builtin_amdgcn_mfma_f32_16x16x32_bf16(pf, vf[dj][ks2],
                                                          o[dj], 0, 0, 0);
      }
    }

    // --- normalize + store (l transpose: q on columns -> rows) ---
    float lT[4];
#pragma unroll
    for (int r = 0; r < 4; r++) lT[r] = 1.f / __shfl(l_st, lq * 4 + r);
#pragma unroll
    for (int r = 0; r < 4; r++) {
      int row = q0 + lq * 4 + r;
#pragma unroll
      for (int dj = 0; dj < 4; dj++)
        Cb[(size_t)row * DM + dj * 16 + lr] = (bf16)(o[dj][r] * lT[r]);
    }
  }
}

// ---------------------------------------------------------------------------
// I/O: ALL inputs float32, output float32 (32 MB). Internals bf16.
// ws (56 MB):  [0,8)MB 4x Wt bf16 | [8,24) Qp | [24,40) Kp | [40,56) Vp/Cx
// d_out reuse: X (bf16 cvt buffer) for projections, then V^T scratch, then
// the final GEMM overwrites d_out with f32 C. Sequential -> no overlap.
// ---------------------------------------------------------------------------
extern "C" void kernel_launch(void* const* d_in, const int* in_sizes, int n_in,
                              void* d_out, int out_size, void* d_ws,
                              size_t ws_size, hipStream_t stream) {
  const float* iq = (const float*)d_in[0];
  const float* ik = (const float*)d_in[1];
  const float* iv = (const float*)d_in[2];
  const float* Wq = (const float*)d_in[3];
  const float* bq = (const float*)d_in[4];
  const float* Wk = (const float*)d_in[5];
  const float* bk = (const float*)d_in[6];
  const float* Wv = (const float*)d_in[7];
  const float* bv = (const float*)d_in[8];
  const float* Wo = (const float*)d_in[9];
  const float* bo = (const float*)d_in[10];

  char* ws = (char*)d_ws;
  const size_t MB = 1024 * 1024;
  bf16* Tq = (bf16*)(ws + 0 * MB);
  bf16* Tk = (bf16*)(ws + 2 * MB);
  bf16* Tv = (bf16*)(ws + 4 * MB);
  bf16* To = (bf16*)(ws + 6 * MB);
  bf16* Qp = (bf16*)(ws + 8 * MB);
  bf16* Kp = (bf16*)(ws + 24 * MB);
  bf16* Vp = (bf16*)(ws + 40 * MB);
  bf16* X = (bf16*)d_out;    // bf16 input-cvt buffer / later V^T scratch
  bf16* Vtp = (bf16*)d_out;  // same region, sequential reuse
  bf16* Cx = Vp;             // ctx aliases V-natural (dead after transpose_v)

  transpose_w_kernel<<<dim3(16, 16, 4), 256, 0, stream>>>(Wq, Wk, Wv, Wo, Tq,
                                                          Tk, Tv, To);
  cvt_kernel<<<dim3(4096), 256, 0, stream>>>(iq, X);
  gemm_bias_kernel<bf16><<<dim3(64, 8), 256, 0, stream>>>(X, Tq, bq, Qp);
  cvt_kernel<<<dim3(4096), 256, 0, stream>>>(ik, X);
  gemm_bias_kernel<bf16><<<dim3(64, 8), 256, 0, stream>>>(X, Tk, bk, Kp);
  cvt_kernel<<<dim3(4096), 256, 0, stream>>>(iv, X);
  gemm_bias_kernel<bf16><<<dim3(64, 8), 256, 0, stream>>>(X, Tv, bv, Vp);
  transpose_v_kernel<<<dim3(32, 16, 4), 256, 0, stream>>>(Vp, Vtp);
  attention_kernel<<<dim3(16, 16, 4), 256, 0, stream>>>(Qp, Kp, Vtp, Cx);
  gemm_bias_kernel<float><<<dim3(64, 8), 256, 0, stream>>>(Cx, To, bo,
                                                           (float*)d_out);
}

// Round 7
// 443.776 us; speedup vs baseline: 1.1913x; 1.1913x over previous
//
#include <hip/hip_runtime.h>
#include <math.h>
#include <type_traits>

typedef __bf16 bf16;
typedef __attribute__((ext_vector_type(8))) __bf16 bf16x8;
typedef __attribute__((ext_vector_type(4))) float f32x4;

#define SEQ 2048
#define DM 1024
#define NH 16
#define HD 64
#define BATCH 4

#define NEG_BIG (-1e30f)
// softmax in exp2 domain: p = 2^(s * (1/8) * log2(e))
#define SCALE_L2E 0.18033688011f

__device__ inline bf16x8 cvt_f32x8(const float* p) {
  f32x4 x0 = *(const f32x4*)p;
  f32x4 x1 = *(const f32x4*)(p + 4);
  bf16x8 r;
  r[0] = (bf16)x0[0]; r[1] = (bf16)x0[1]; r[2] = (bf16)x0[2]; r[3] = (bf16)x0[3];
  r[4] = (bf16)x1[0]; r[5] = (bf16)x1[1]; r[6] = (bf16)x1[2]; r[7] = (bf16)x1[3];
  return r;
}

// async global->LDS DMA, 16 B per lane; LDS dest is wave-uniform base, HW
// writes lane i at base + i*16 (m97 pattern).
__device__ inline void async_copy16(const bf16* g, bf16* l) {
  __builtin_amdgcn_global_load_lds(
      (const __attribute__((address_space(1))) unsigned int*)g,
      (__attribute__((address_space(3))) unsigned int*)l, 16, 0, 0);
}

// ---------------------------------------------------------------------------
// f32 -> bf16 elementwise convert (memory-bound pre-pass), 8 elems/thread.
// ---------------------------------------------------------------------------
__global__ __launch_bounds__(256) void cvt_kernel(const float* __restrict__ src,
                                                  bf16* __restrict__ dst) {
  size_t i = ((size_t)blockIdx.x * 256 + threadIdx.x) * 8;
  *(bf16x8*)(dst + i) = cvt_f32x8(src + i);
}

// ---------------------------------------------------------------------------
// Weight transpose + f32->bf16 convert: Wt[n][k] = (bf16)W[k][n], 1024x1024.
// ---------------------------------------------------------------------------
__global__ __launch_bounds__(256) void transpose_w_kernel(
    const float* __restrict__ Wq, const float* __restrict__ Wk,
    const float* __restrict__ Wv, const float* __restrict__ Wo,
    bf16* __restrict__ Tq, bf16* __restrict__ Tk,
    bf16* __restrict__ Tv, bf16* __restrict__ To) {
  __shared__ bf16 tile[64 * 66];
  int z = blockIdx.z;
  const float* src = (z == 0) ? Wq : (z == 1) ? Wk : (z == 2) ? Wv : Wo;
  bf16* dst = (z == 0) ? Tq : (z == 1) ? Tk : (z == 2) ? Tv : To;
  int n0 = blockIdx.x * 64, k0 = blockIdx.y * 64;
  int t = threadIdx.x;
  int c = t & 63, rr = t >> 6;
#pragma unroll
  for (int i = 0; i < 16; i++) {
    int k = i * 4 + rr;
    tile[k * 66 + c] = (bf16)src[(size_t)(k0 + k) * DM + n0 + c];
  }
  __syncthreads();
#pragma unroll
  for (int i = 0; i < 16; i++) {
    int n = i * 4 + rr;
    dst[(size_t)(n0 + n) * DM + k0 + c] = tile[c * 66 + n];
  }
}

// ---------------------------------------------------------------------------
// V transpose (bf16 -> bf16): Vn[b,s,h*64+d] -> Vt[((b*16+h)*64+d)*2048 + s]
// ---------------------------------------------------------------------------
__global__ __launch_bounds__(256) void transpose_v_kernel(
    const bf16* __restrict__ Vn, bf16* __restrict__ Vt) {
  __shared__ bf16 tile[64 * 66];
  int s0 = blockIdx.x * 64;
  int h = blockIdx.y, b = blockIdx.z;
  int t = threadIdx.x;
  int c = t & 63, rr = t >> 6;
#pragma unroll
  for (int i = 0; i < 16; i++) {
    int s = i * 4 + rr;
    tile[s * 66 + c] = Vn[((size_t)(b * SEQ + s0 + s)) * DM + h * HD + c];
  }
  __syncthreads();
#pragma unroll
  for (int i = 0; i < 16; i++) {
    int d = i * 4 + rr;
    Vt[((size_t)(b * NH + h) * HD + d) * SEQ + s0 + c] = tile[c * 66 + d];
  }
}

// ---------------------------------------------------------------------------
// GEMM + bias v3: C[8192,1024] = A @ Bt^T + bias.
// k-outer LDS layout [kc 0..7][row 0..127][8] (m97-proven): ds_read_b128
// bank phase = (4*lr+d)%32 -> 2-way aliasing only (free per m136). Round-5's
// row-major layout was 8-way conflicted (bank = f(lr&1, lq) only).
// BK=64: 16 K-iterations (half the barrier drains of BK=32).
// DMA: wave w stages kc in {w, w+4}, halves 0/1 -> 4 instr per matrix per
// wave per iteration; lane i covers row half*64+i (16B strided, m97 pattern).
// ---------------------------------------------------------------------------
template <typename CT>
__global__ __launch_bounds__(256) void gemm_bias_kernel(
    const bf16* __restrict__ A, const bf16* __restrict__ Bt,
    const float* __restrict__ bias, CT* __restrict__ C) {
  __shared__ bf16 As[8 * 128 * 8];  // 16 KB
  __shared__ bf16 Bs[8 * 128 * 8];  // 16 KB
  int m0 = blockIdx.x * 128, n0 = blockIdx.y * 128;
  int t = threadIdx.x;
  int wave = t >> 6, lane = t & 63, lr = lane & 15, lq = lane >> 4;
  int wm = (wave & 1) * 64, wn = (wave >> 1) * 64;

  f32x4 acc[4][4];
#pragma unroll
  for (int i = 0; i < 4; i++)
#pragma unroll
    for (int j = 0; j < 4; j++) acc[i][j] = (f32x4){0.f, 0.f, 0.f, 0.f};

  // DMA pointers: kcA = wave, kcB = wave+4; halves 0/1; lane i -> row.
  int kcl = wave, kch = wave + 4;
  const bf16* gA_l0 = A + (size_t)(m0 + lane) * DM + kcl * 8;
  const bf16* gA_l1 = A + (size_t)(m0 + 64 + lane) * DM + kcl * 8;
  const bf16* gA_h0 = A + (size_t)(m0 + lane) * DM + kch * 8;
  const bf16* gA_h1 = A + (size_t)(m0 + 64 + lane) * DM + kch * 8;
  const bf16* gB_l0 = Bt + (size_t)(n0 + lane) * DM + kcl * 8;
  const bf16* gB_l1 = Bt + (size_t)(n0 + 64 + lane) * DM + kcl * 8;
  const bf16* gB_h0 = Bt + (size_t)(n0 + lane) * DM + kch * 8;
  const bf16* gB_h1 = Bt + (size_t)(n0 + 64 + lane) * DM + kch * 8;
  bf16* lA_l0 = &As[(kcl * 128 + 0) * 8];
  bf16* lA_l1 = &As[(kcl * 128 + 64) * 8];
  bf16* lA_h0 = &As[(kch * 128 + 0) * 8];
  bf16* lA_h1 = &As[(kch * 128 + 64) * 8];
  bf16* lB_l0 = &Bs[(kcl * 128 + 0) * 8];
  bf16* lB_l1 = &Bs[(kcl * 128 + 64) * 8];
  bf16* lB_h0 = &Bs[(kch * 128 + 0) * 8];
  bf16* lB_h1 = &Bs[(kch * 128 + 64) * 8];

  for (int k0 = 0; k0 < DM; k0 += 64) {
    async_copy16(gA_l0, lA_l0);
    async_copy16(gA_l1, lA_l1);
    async_copy16(gA_h0, lA_h0);
    async_copy16(gA_h1, lA_h1);
    async_copy16(gB_l0, lB_l0);
    async_copy16(gB_l1, lB_l1);
    async_copy16(gB_h0, lB_h0);
    async_copy16(gB_h1, lB_h1);
    gA_l0 += 64; gA_l1 += 64; gA_h0 += 64; gA_h1 += 64;
    gB_l0 += 64; gB_l1 += 64; gB_h0 += 64; gB_h1 += 64;
    __syncthreads();  // drains vmcnt -> DMA complete

#pragma unroll
    for (int kb = 0; kb < 2; kb++) {
      int kc = kb * 4 + lq;
      bf16x8 af[4], bfr[4];
#pragma unroll
      for (int i = 0; i < 4; i++)
        af[i] = *(const bf16x8*)&As[(kc * 128 + wm + i * 16 + lr) * 8];
#pragma unroll
      for (int j = 0; j < 4; j++)
        bfr[j] = *(const bf16x8*)&Bs[(kc * 128 + wn + j * 16 + lr) * 8];
#pragma unroll
      for (int i = 0; i < 4; i++)
#pragma unroll
        for (int j = 0; j < 4; j++)
          acc[i][j] = __builtin_amdgcn_mfma_f32_16x16x32_bf16(
              af[i], bfr[j], acc[i][j], 0, 0, 0);
    }
    __syncthreads();
  }

  // Epilogue: C/D layout col = lane&15, row = (lane>>4)*4 + reg
#pragma unroll
  for (int j = 0; j < 4; j++) {
    int col = n0 + wn + j * 16 + lr;
    float bv = bias[col];
#pragma unroll
    for (int i = 0; i < 4; i++) {
      int row = m0 + wm + i * 16 + lq * 4;
#pragma unroll
      for (int r = 0; r < 4; r++) {
        C[(size_t)(row + r) * DM + col] = (CT)(acc[i][j][r] + bv);
      }
    }
  }
}

// ---------------------------------------------------------------------------
// Flash attention v2 (causal) — REVERTED to the measured-141us round-4
// version: zero LDS, zero barriers, wave-independent; 32-row q-tile pairs
// (p, 63-p), 2048 waves. v3's 16-row split doubled the per-wave-redundant
// K/V loads and runtime doubled with them (request-bound) — do not shrink
// tiles below 32 rows.
// ---------------------------------------------------------------------------
__global__ __launch_bounds__(256, 2) void attention_kernel(
    const bf16* __restrict__ Q, const bf16* __restrict__ K,
    const bf16* __restrict__ Vt, bf16* __restrict__ ctx) {
  int h = blockIdx.y, b = blockIdx.z;
  int t = threadIdx.x, wave = t >> 6, lane = t & 63, lr = lane & 15,
      lq = lane >> 4;
  int p = blockIdx.x * 4 + wave;  // pair index in [0,32)

  const bf16* Qb = Q + (size_t)b * SEQ * DM + h * HD;
  const bf16* Kb = K + (size_t)b * SEQ * DM + h * HD;
  const bf16* Vb = Vt + (size_t)(b * NH + h) * HD * SEQ;
  bf16* Cb = ctx + (size_t)b * SEQ * DM + h * HD;

#pragma unroll 1
  for (int pass = 0; pass < 2; pass++) {
    int tq = pass ? (63 - p) : p;
    int q0 = tq * 32;

    bf16x8 qf[2][2];
#pragma unroll
    for (int qi = 0; qi < 2; qi++)
#pragma unroll
      for (int ks = 0; ks < 2; ks++)
        qf[qi][ks] = *(const bf16x8*)&Qb[(size_t)(q0 + qi * 16 + lr) * DM +
                                         ks * 32 + lq * 8];

    f32x4 o[2][4];
    float m_st[2], l_st[2];
#pragma unroll
    for (int mi = 0; mi < 2; mi++) {
#pragma unroll
      for (int dj = 0; dj < 4; dj++) o[mi][dj] = (f32x4){0.f, 0.f, 0.f, 0.f};
      m_st[mi] = NEG_BIG;
      l_st[mi] = 0.f;
    }

    int kv_end = q0 + 32;
#pragma unroll 1
    for (int kv0 = 0; kv0 < kv_end; kv0 += 64) {
      bf16x8 kf[4][2];
#pragma unroll
      for (int kvt = 0; kvt < 4; kvt++)
#pragma unroll
        for (int ks = 0; ks < 2; ks++)
          kf[kvt][ks] = *(const bf16x8*)&Kb[(size_t)(kv0 + kvt * 16 + lr) * DM +
                                            ks * 32 + lq * 8];
      bf16x8 vf[4][2];
#pragma unroll
      for (int dj = 0; dj < 4; dj++)
#pragma unroll
        for (int ks2 = 0; ks2 < 2; ks2++)
          vf[dj][ks2] = *(const bf16x8*)&Vb[(size_t)(dj * 16 + lr) * SEQ + kv0 +
                                            ks2 * 32 + lq * 8];

      f32x4 s[4][2];
#pragma unroll
      for (int kvt = 0; kvt < 4; kvt++)
#pragma unroll
        for (int qi = 0; qi < 2; qi++) {
          f32x4 acc = (f32x4){0.f, 0.f, 0.f, 0.f};
          acc = __builtin_amdgcn_mfma_f32_16x16x32_bf16(kf[kvt][0], qf[qi][0],
                                                        acc, 0, 0, 0);
          acc = __builtin_amdgcn_mfma_f32_16x16x32_bf16(kf[kvt][1], qf[qi][1],
                                                        acc, 0, 0, 0);
          s[kvt][qi] = acc;
        }

      if (kv0 + 63 > q0) {
#pragma unroll
        for (int kvt = 0; kvt < 4; kvt++)
#pragma unroll
          for (int qi = 0; qi < 2; qi++)
#pragma unroll
            for (int r = 0; r < 4; r++) {
              int kv_g = kv0 + kvt * 16 + lq * 4 + r;
              int q_g = q0 + qi * 16 + lr;
              float v = s[kvt][qi][r] * SCALE_L2E;
              s[kvt][qi][r] = (kv_g > q_g) ? NEG_BIG : v;
            }
      } else {
#pragma unroll
        for (int kvt = 0; kvt < 4; kvt++)
#pragma unroll
          for (int qi = 0; qi < 2; qi++)
#pragma unroll
            for (int r = 0; r < 4; r++) s[kvt][qi][r] *= SCALE_L2E;
      }

      float alpha[2];
#pragma unroll
      for (int qi = 0; qi < 2; qi++) {
        float mx = s[0][qi][0];
#pragma unroll
        for (int kvt = 0; kvt < 4; kvt++)
#pragma unroll
          for (int r = 0; r < 4; r++) mx = fmaxf(mx, s[kvt][qi][r]);
        mx = fmaxf(mx, __shfl_xor(mx, 16));
        mx = fmaxf(mx, __shfl_xor(mx, 32));
        float mnew = fmaxf(m_st[qi], mx);
        alpha[qi] = exp2f(m_st[qi] - mnew);
        m_st[qi] = mnew;
        float rs = 0.f;
#pragma unroll
        for (int kvt = 0; kvt < 4; kvt++)
#pragma unroll
          for (int r = 0; r < 4; r++) {
            float pv = exp2f(s[kvt][qi][r] - mnew);
            s[kvt][qi][r] = pv;
            rs += pv;
          }
        rs += __shfl_xor(rs, 16);
        rs += __shfl_xor(rs, 32);
        l_st[qi] = l_st[qi] * alpha[qi] + rs;
      }

      float aT[2][4];
#pragma unroll
      for (int mi = 0; mi < 2; mi++)
#pragma unroll
        for (int r = 0; r < 4; r++) aT[mi][r] = __shfl(alpha[mi], lq * 4 + r);
#pragma unroll
      for (int mi = 0; mi < 2; mi++)
#pragma unroll
        for (int dj = 0; dj < 4; dj++)
#pragma unroll
          for (int r = 0; r < 4; r++) o[mi][dj][r] *= aT[mi][r];

      int src_base = (lq & 1) * 32 + lr;
      bool hi = (lq >> 1) != 0;
#pragma unroll
      for (int ks2 = 0; ks2 < 2; ks2++) {
        bf16x8 pf[2];
#pragma unroll
        for (int mi = 0; mi < 2; mi++) {
#pragma unroll
          for (int j = 0; j < 8; j++) {
            int src = src_base + (j >> 2) * 16;
            float v0 = __shfl(s[2 * ks2][mi][j & 3], src);
            float v1 = __shfl(s[2 * ks2 + 1][mi][j & 3], src);
            pf[mi][j] = (bf16)(hi ? v1 : v0);
          }
        }
#pragma unroll
        for (int dj = 0; dj < 4; dj++) {
          o[0][dj] = __builtin_amdgcn_mfma_f32_16x16x32_bf16(pf[0], vf[dj][ks2],
                                                             o[0][dj], 0, 0, 0);
          o[1][dj] = __builtin_amdgcn_mfma_f32_16x16x32_bf16(pf[1], vf[dj][ks2],
                                                             o[1][dj], 0, 0, 0);
        }
      }
    }

    float lT[2][4];
#pragma unroll
    for (int mi = 0; mi < 2; mi++)
#pragma unroll
      for (int r = 0; r < 4; r++)
        lT[mi][r] = 1.f / __shfl(l_st[mi], lq * 4 + r);
#pragma unroll
    for (int mi = 0; mi < 2; mi++)
#pragma unroll
      for (int r = 0; r < 4; r++) {
        int row = q0 + mi * 16 + lq * 4 + r;
#pragma unroll
        for (int dj = 0; dj < 4; dj++)
          Cb[(size_t)row * DM + dj * 16 + lr] = (bf16)(o[mi][dj][r] * lT[mi][r]);
      }
  }
}

// ---------------------------------------------------------------------------
// I/O: ALL inputs float32, output float32 (32 MB). Internals bf16.
// ws (56 MB):  [0,8)MB 4x Wt bf16 | [8,24) Qp | [24,40) Kp | [40,56) Vp/Cx
// d_out reuse: X (bf16 cvt buffer) for projections, then V^T scratch, then
// the final GEMM overwrites d_out with f32 C. Sequential -> no overlap.
// ---------------------------------------------------------------------------
extern "C" void kernel_launch(void* const* d_in, const int* in_sizes, int n_in,
                              void* d_out, int out_size, void* d_ws,
                              size_t ws_size, hipStream_t stream) {
  const float* iq = (const float*)d_in[0];
  const float* ik = (const float*)d_in[1];
  const float* iv = (const float*)d_in[2];
  const float* Wq = (const float*)d_in[3];
  const float* bq = (const float*)d_in[4];
  const float* Wk = (const float*)d_in[5];
  const float* bk = (const float*)d_in[6];
  const float* Wv = (const float*)d_in[7];
  const float* bv = (const float*)d_in[8];
  const float* Wo = (const float*)d_in[9];
  const float* bo = (const float*)d_in[10];

  char* ws = (char*)d_ws;
  const size_t MB = 1024 * 1024;
  bf16* Tq = (bf16*)(ws + 0 * MB);
  bf16* Tk = (bf16*)(ws + 2 * MB);
  bf16* Tv = (bf16*)(ws + 4 * MB);
  bf16* To = (bf16*)(ws + 6 * MB);
  bf16* Qp = (bf16*)(ws + 8 * MB);
  bf16* Kp = (bf16*)(ws + 24 * MB);
  bf16* Vp = (bf16*)(ws + 40 * MB);
  bf16* X = (bf16*)d_out;    // bf16 input-cvt buffer / later V^T scratch
  bf16* Vtp = (bf16*)d_out;  // same region, sequential reuse
  bf16* Cx = Vp;             // ctx aliases V-natural (dead after transpose_v)

  transpose_w_kernel<<<dim3(16, 16, 4), 256, 0, stream>>>(Wq, Wk, Wv, Wo, Tq,
                                                          Tk, Tv, To);
  cvt_kernel<<<dim3(4096), 256, 0, stream>>>(iq, X);
  gemm_bias_kernel<bf16><<<dim3(64, 8), 256, 0, stream>>>(X, Tq, bq, Qp);
  cvt_kernel<<<dim3(4096), 256, 0, stream>>>(ik, X);
  gemm_bias_kernel<bf16><<<dim3(64, 8), 256, 0, stream>>>(X, Tk, bk, Kp);
  cvt_kernel<<<dim3(4096), 256, 0, stream>>>(iv, X);
  gemm_bias_kernel<bf16><<<dim3(64, 8), 256, 0, stream>>>(X, Tv, bv, Vp);
  transpose_v_kernel<<<dim3(32, 16, 4), 256, 0, stream>>>(Vp, Vtp);
  attention_kernel<<<dim3(8, 16, 4), 256, 0, stream>>>(Qp, Kp, Vtp, Cx);
  gemm_bias_kernel<float><<<dim3(64, 8), 256, 0, stream>>>(Cx, To, bo,
                                                           (float*)d_out);
}

// Round 8
// 400.480 us; speedup vs baseline: 1.3201x; 1.1081x over previous
//
#include <hip/hip_runtime.h>
#include <math.h>
#include <type_traits>

typedef __bf16 bf16;
typedef __attribute__((ext_vector_type(8))) __bf16 bf16x8;
typedef __attribute__((ext_vector_type(4))) float f32x4;

#define SEQ 2048
#define DM 1024
#define NH 16
#define HD 64
#define BATCH 4

#define NEG_BIG (-1e30f)
// softmax in exp2 domain: p = 2^(s * (1/8) * log2(e))
#define SCALE_L2E 0.18033688011f

__device__ inline bf16x8 cvt_f32x8(const float* p) {
  f32x4 x0 = *(const f32x4*)p;
  f32x4 x1 = *(const f32x4*)(p + 4);
  bf16x8 r;
  r[0] = (bf16)x0[0]; r[1] = (bf16)x0[1]; r[2] = (bf16)x0[2]; r[3] = (bf16)x0[3];
  r[4] = (bf16)x1[0]; r[5] = (bf16)x1[1]; r[6] = (bf16)x1[2]; r[7] = (bf16)x1[3];
  return r;
}

// async global->LDS DMA, 16 B per lane; LDS dest is wave-uniform base, HW
// writes lane i at base + i*16 (m97 pattern).
__device__ inline void async_copy16(const bf16* g, bf16* l) {
  __builtin_amdgcn_global_load_lds(
      (const __attribute__((address_space(1))) unsigned int*)g,
      (__attribute__((address_space(3))) unsigned int*)l, 16, 0, 0);
}

// ---------------------------------------------------------------------------
// f32 -> bf16 elementwise convert (memory-bound pre-pass), 8 elems/thread.
// ---------------------------------------------------------------------------
__global__ __launch_bounds__(256) void cvt_kernel(const float* __restrict__ src,
                                                  bf16* __restrict__ dst) {
  size_t i = ((size_t)blockIdx.x * 256 + threadIdx.x) * 8;
  *(bf16x8*)(dst + i) = cvt_f32x8(src + i);
}

// ---------------------------------------------------------------------------
// Weight transpose + f32->bf16 convert: Wt[n][k] = (bf16)W[k][n], 1024x1024.
// ---------------------------------------------------------------------------
__global__ __launch_bounds__(256) void transpose_w_kernel(
    const float* __restrict__ Wq, const float* __restrict__ Wk,
    const float* __restrict__ Wv, const float* __restrict__ Wo,
    bf16* __restrict__ Tq, bf16* __restrict__ Tk,
    bf16* __restrict__ Tv, bf16* __restrict__ To) {
  __shared__ bf16 tile[64 * 66];
  int z = blockIdx.z;
  const float* src = (z == 0) ? Wq : (z == 1) ? Wk : (z == 2) ? Wv : Wo;
  bf16* dst = (z == 0) ? Tq : (z == 1) ? Tk : (z == 2) ? Tv : To;
  int n0 = blockIdx.x * 64, k0 = blockIdx.y * 64;
  int t = threadIdx.x;
  int c = t & 63, rr = t >> 6;
#pragma unroll
  for (int i = 0; i < 16; i++) {
    int k = i * 4 + rr;
    tile[k * 66 + c] = (bf16)src[(size_t)(k0 + k) * DM + n0 + c];
  }
  __syncthreads();
#pragma unroll
  for (int i = 0; i < 16; i++) {
    int n = i * 4 + rr;
    dst[(size_t)(n0 + n) * DM + k0 + c] = tile[c * 66 + n];
  }
}

// ---------------------------------------------------------------------------
// V transpose from COMPACT per-head layout:
//   Vc[((b*16+h)*2048 + s)*64 + d]  ->  Vt[((b*16+h)*64 + d)*2048 + s]
// ---------------------------------------------------------------------------
__global__ __launch_bounds__(256) void transpose_v_kernel(
    const bf16* __restrict__ Vc, bf16* __restrict__ Vt) {
  __shared__ bf16 tile[64 * 66];
  int s0 = blockIdx.x * 64;
  int bh = blockIdx.y;  // b*16+h
  int t = threadIdx.x;
  int c = t & 63, rr = t >> 6;
  const bf16* src = Vc + (size_t)bh * SEQ * HD;
  bf16* dst = Vt + (size_t)bh * HD * SEQ;
#pragma unroll
  for (int i = 0; i < 16; i++) {
    int s = i * 4 + rr;
    tile[s * 66 + c] = src[(size_t)(s0 + s) * HD + c];
  }
  __syncthreads();
#pragma unroll
  for (int i = 0; i < 16; i++) {
    int d = i * 4 + rr;
    dst[(size_t)d * SEQ + s0 + c] = tile[c * 66 + d];
  }
}

// ---------------------------------------------------------------------------
// GEMM + bias (round-5 version — measured faster than the k-outer/BK=64
// variant: its 64B-grouped DMA segments beat round-7's 16B-scattered ones;
// this kernel is request-throughput bound, not bank-conflict bound).
// MODE 0: C[row*1024+col] (type CT).  MODE 1: compact per-head bf16
// C[((b*16+h)*2048+s)*64+d] with b=row>>11, s=row&2047, h=col>>6, d=col&63.
// ---------------------------------------------------------------------------
template <typename CT, int MODE>
__global__ __launch_bounds__(256) void gemm_bias_kernel(
    const bf16* __restrict__ A, const bf16* __restrict__ Bt,
    const float* __restrict__ bias, CT* __restrict__ C) {
  __shared__ bf16 As[128 * 32];
  __shared__ bf16 Bs[128 * 32];
  int m0 = blockIdx.x * 128, n0 = blockIdx.y * 128;
  int t = threadIdx.x;
  int wave = t >> 6, lane = t & 63, lr = lane & 15, lq = lane >> 4;
  int wm = (wave & 1) * 64, wn = (wave >> 1) * 64;

  f32x4 acc[4][4];
#pragma unroll
  for (int i = 0; i < 4; i++)
#pragma unroll
    for (int j = 0; j < 4; j++) acc[i][j] = (f32x4){0.f, 0.f, 0.f, 0.f};

  // staging: wave w, chunk c: slot = w*128 + c*64 + lane; row = slot>>2,
  // kc = lane&3. 4 lanes cover 64 contiguous global bytes (16 segs/instr).
  int srow = wave * 32 + (lane >> 2);
  int skc = lane & 3;
  const bf16* gA0 = A + (size_t)(m0 + srow) * DM + skc * 8;
  const bf16* gA1 = gA0 + (size_t)16 * DM;
  const bf16* gB0 = Bt + (size_t)(n0 + srow) * DM + skc * 8;
  const bf16* gB1 = gB0 + (size_t)16 * DM;
  bf16* lA0 = &As[(wave * 128) * 8];
  bf16* lA1 = &As[(wave * 128 + 64) * 8];
  bf16* lB0 = &Bs[(wave * 128) * 8];
  bf16* lB1 = &Bs[(wave * 128 + 64) * 8];

  for (int k0 = 0; k0 < DM; k0 += 32) {
    async_copy16(gA0, lA0);
    async_copy16(gA1, lA1);
    async_copy16(gB0, lB0);
    async_copy16(gB1, lB1);
    gA0 += 32; gA1 += 32; gB0 += 32; gB1 += 32;
    __syncthreads();

    bf16x8 af[4], bfr[4];
#pragma unroll
    for (int i = 0; i < 4; i++)
      af[i] = *(const bf16x8*)&As[(wm + i * 16 + lr) * 32 + lq * 8];
#pragma unroll
    for (int j = 0; j < 4; j++)
      bfr[j] = *(const bf16x8*)&Bs[(wn + j * 16 + lr) * 32 + lq * 8];
#pragma unroll
    for (int i = 0; i < 4; i++)
#pragma unroll
      for (int j = 0; j < 4; j++)
        acc[i][j] = __builtin_amdgcn_mfma_f32_16x16x32_bf16(af[i], bfr[j],
                                                            acc[i][j], 0, 0, 0);
    __syncthreads();
  }

  // Epilogue: C/D layout col = lane&15, row = (lane>>4)*4 + reg
#pragma unroll
  for (int j = 0; j < 4; j++) {
    int col = n0 + wn + j * 16 + lr;
    float bv = bias[col];
#pragma unroll
    for (int i = 0; i < 4; i++) {
      int row0 = m0 + wm + i * 16 + lq * 4;
#pragma unroll
      for (int r = 0; r < 4; r++) {
        int row = row0 + r;
        float v = acc[i][j][r] + bv;
        if constexpr (MODE == 0) {
          C[(size_t)row * DM + col] = (CT)v;
        } else {
          int b = row >> 11, s = row & 2047, h = col >> 6, d = col & 63;
          C[((size_t)(b * NH + h) * SEQ + s) * HD + d] = (CT)v;
        }
      }
    }
  }
}

// ---------------------------------------------------------------------------
// Flash attention v4 (causal): zero LDS/barriers, wave-independent, 32-row
// q-tile pairs (p, 63-p), 2048 waves — round-4 structure, but Q and K now
// read from COMPACT per-head layout [B,H,S,64] (row pitch 128B instead of
// 2KB): each 16B/lane fragment load coalesces into 16x64B segments instead
// of 64x16B -> ~2.5x fewer memory requests (the measured binding resource).
// ---------------------------------------------------------------------------
__global__ __launch_bounds__(256, 2) void attention_kernel(
    const bf16* __restrict__ Qc, const bf16* __restrict__ Kc,
    const bf16* __restrict__ Vt, bf16* __restrict__ ctx) {
  int h = blockIdx.y, b = blockIdx.z;
  int t = threadIdx.x, wave = t >> 6, lane = t & 63, lr = lane & 15,
      lq = lane >> 4;
  int p = blockIdx.x * 4 + wave;  // pair index in [0,32)

  const bf16* Qb = Qc + (size_t)(b * NH + h) * SEQ * HD;
  const bf16* Kb = Kc + (size_t)(b * NH + h) * SEQ * HD;
  const bf16* Vb = Vt + (size_t)(b * NH + h) * HD * SEQ;
  bf16* Cb = ctx + (size_t)b * SEQ * DM + h * HD;

#pragma unroll 1
  for (int pass = 0; pass < 2; pass++) {
    int tq = pass ? (63 - p) : p;
    int q0 = tq * 32;

    bf16x8 qf[2][2];
#pragma unroll
    for (int qi = 0; qi < 2; qi++)
#pragma unroll
      for (int ks = 0; ks < 2; ks++)
        qf[qi][ks] = *(const bf16x8*)&Qb[(size_t)(q0 + qi * 16 + lr) * HD +
                                         ks * 32 + lq * 8];

    f32x4 o[2][4];
    float m_st[2], l_st[2];
#pragma unroll
    for (int mi = 0; mi < 2; mi++) {
#pragma unroll
      for (int dj = 0; dj < 4; dj++) o[mi][dj] = (f32x4){0.f, 0.f, 0.f, 0.f};
      m_st[mi] = NEG_BIG;
      l_st[mi] = 0.f;
    }

    int kv_end = q0 + 32;
#pragma unroll 1
    for (int kv0 = 0; kv0 < kv_end; kv0 += 64) {
      bf16x8 kf[4][2];
#pragma unroll
      for (int kvt = 0; kvt < 4; kvt++)
#pragma unroll
        for (int ks = 0; ks < 2; ks++)
          kf[kvt][ks] = *(const bf16x8*)&Kb[(size_t)(kv0 + kvt * 16 + lr) * HD +
                                            ks * 32 + lq * 8];
      bf16x8 vf[4][2];
#pragma unroll
      for (int dj = 0; dj < 4; dj++)
#pragma unroll
        for (int ks2 = 0; ks2 < 2; ks2++)
          vf[dj][ks2] = *(const bf16x8*)&Vb[(size_t)(dj * 16 + lr) * SEQ + kv0 +
                                            ks2 * 32 + lq * 8];

      f32x4 s[4][2];
#pragma unroll
      for (int kvt = 0; kvt < 4; kvt++)
#pragma unroll
        for (int qi = 0; qi < 2; qi++) {
          f32x4 acc = (f32x4){0.f, 0.f, 0.f, 0.f};
          acc = __builtin_amdgcn_mfma_f32_16x16x32_bf16(kf[kvt][0], qf[qi][0],
                                                        acc, 0, 0, 0);
          acc = __builtin_amdgcn_mfma_f32_16x16x32_bf16(kf[kvt][1], qf[qi][1],
                                                        acc, 0, 0, 0);
          s[kvt][qi] = acc;
        }

      if (kv0 + 63 > q0) {
#pragma unroll
        for (int kvt = 0; kvt < 4; kvt++)
#pragma unroll
          for (int qi = 0; qi < 2; qi++)
#pragma unroll
            for (int r = 0; r < 4; r++) {
              int kv_g = kv0 + kvt * 16 + lq * 4 + r;
              int q_g = q0 + qi * 16 + lr;
              float v = s[kvt][qi][r] * SCALE_L2E;
              s[kvt][qi][r] = (kv_g > q_g) ? NEG_BIG : v;
            }
      } else {
#pragma unroll
        for (int kvt = 0; kvt < 4; kvt++)
#pragma unroll
          for (int qi = 0; qi < 2; qi++)
#pragma unroll
            for (int r = 0; r < 4; r++) s[kvt][qi][r] *= SCALE_L2E;
      }

      float alpha[2];
#pragma unroll
      for (int qi = 0; qi < 2; qi++) {
        float mx = s[0][qi][0];
#pragma unroll
        for (int kvt = 0; kvt < 4; kvt++)
#pragma unroll
          for (int r = 0; r < 4; r++) mx = fmaxf(mx, s[kvt][qi][r]);
        mx = fmaxf(mx, __shfl_xor(mx, 16));
        mx = fmaxf(mx, __shfl_xor(mx, 32));
        float mnew = fmaxf(m_st[qi], mx);
        alpha[qi] = exp2f(m_st[qi] - mnew);
        m_st[qi] = mnew;
        float rs = 0.f;
#pragma unroll
        for (int kvt = 0; kvt < 4; kvt++)
#pragma unroll
          for (int r = 0; r < 4; r++) {
            float pv = exp2f(s[kvt][qi][r] - mnew);
            s[kvt][qi][r] = pv;
            rs += pv;
          }
        rs += __shfl_xor(rs, 16);
        rs += __shfl_xor(rs, 32);
        l_st[qi] = l_st[qi] * alpha[qi] + rs;
      }

      float aT[2][4];
#pragma unroll
      for (int mi = 0; mi < 2; mi++)
#pragma unroll
        for (int r = 0; r < 4; r++) aT[mi][r] = __shfl(alpha[mi], lq * 4 + r);
#pragma unroll
      for (int mi = 0; mi < 2; mi++)
#pragma unroll
        for (int dj = 0; dj < 4; dj++)
#pragma unroll
          for (int r = 0; r < 4; r++) o[mi][dj][r] *= aT[mi][r];

      int src_base = (lq & 1) * 32 + lr;
      bool hi = (lq >> 1) != 0;
#pragma unroll
      for (int ks2 = 0; ks2 < 2; ks2++) {
        bf16x8 pf[2];
#pragma unroll
        for (int mi = 0; mi < 2; mi++) {
#pragma unroll
          for (int j = 0; j < 8; j++) {
            int src = src_base + (j >> 2) * 16;
            float v0 = __shfl(s[2 * ks2][mi][j & 3], src);
            float v1 = __shfl(s[2 * ks2 + 1][mi][j & 3], src);
            pf[mi][j] = (bf16)(hi ? v1 : v0);
          }
        }
#pragma unroll
        for (int dj = 0; dj < 4; dj++) {
          o[0][dj] = __builtin_amdgcn_mfma_f32_16x16x32_bf16(pf[0], vf[dj][ks2],
                                                             o[0][dj], 0, 0, 0);
          o[1][dj] = __builtin_amdgcn_mfma_f32_16x16x32_bf16(pf[1], vf[dj][ks2],
                                                             o[1][dj], 0, 0, 0);
        }
      }
    }

    float lT[2][4];
#pragma unroll
    for (int mi = 0; mi < 2; mi++)
#pragma unroll
      for (int r = 0; r < 4; r++)
        lT[mi][r] = 1.f / __shfl(l_st[mi], lq * 4 + r);
#pragma unroll
    for (int mi = 0; mi < 2; mi++)
#pragma unroll
      for (int r = 0; r < 4; r++) {
        int row = q0 + mi * 16 + lq * 4 + r;
#pragma unroll
        for (int dj = 0; dj < 4; dj++)
          Cb[(size_t)row * DM + dj * 16 + lr] = (bf16)(o[mi][dj][r] * lT[mi][r]);
      }
  }
}

// ---------------------------------------------------------------------------
// I/O: ALL inputs float32, output float32 (32 MB). Internals bf16.
// ws (56 MB):  [0,8)MB 4x Wt bf16 | [8,24) Qc compact | [24,40) Kc compact |
// [40,56) Vc compact, later ctx.  d_out reuse: X (bf16 cvt buffer), then V^T
// scratch, then final f32 C. Sequential on one stream -> no liveness overlap.
// ---------------------------------------------------------------------------
extern "C" void kernel_launch(void* const* d_in, const int* in_sizes, int n_in,
                              void* d_out, int out_size, void* d_ws,
                              size_t ws_size, hipStream_t stream) {
  const float* iq = (const float*)d_in[0];
  const float* ik = (const float*)d_in[1];
  const float* iv = (const float*)d_in[2];
  const float* Wq = (const float*)d_in[3];
  const float* bq = (const float*)d_in[4];
  const float* Wk = (const float*)d_in[5];
  const float* bk = (const float*)d_in[6];
  const float* Wv = (const float*)d_in[7];
  const float* bv = (const float*)d_in[8];
  const float* Wo = (const float*)d_in[9];
  const float* bo = (const float*)d_in[10];

  char* ws = (char*)d_ws;
  const size_t MB = 1024 * 1024;
  bf16* Tq = (bf16*)(ws + 0 * MB);
  bf16* Tk = (bf16*)(ws + 2 * MB);
  bf16* Tv = (bf16*)(ws + 4 * MB);
  bf16* To = (bf16*)(ws + 6 * MB);
  bf16* Qc = (bf16*)(ws + 8 * MB);   // compact [B,H,S,64]
  bf16* Kc = (bf16*)(ws + 24 * MB);  // compact [B,H,S,64]
  bf16* Vc = (bf16*)(ws + 40 * MB);  // compact [B,H,S,64]
  bf16* X = (bf16*)d_out;    // bf16 input-cvt buffer / later V^T scratch
  bf16* Vtp = (bf16*)d_out;  // same region, sequential reuse
  bf16* Cx = Vc;             // ctx aliases Vc (dead after transpose_v)

  transpose_w_kernel<<<dim3(16, 16, 4), 256, 0, stream>>>(Wq, Wk, Wv, Wo, Tq,
                                                          Tk, Tv, To);
  cvt_kernel<<<dim3(4096), 256, 0, stream>>>(iq, X);
  gemm_bias_kernel<bf16, 1><<<dim3(64, 8), 256, 0, stream>>>(X, Tq, bq, Qc);
  cvt_kernel<<<dim3(4096), 256, 0, stream>>>(ik, X);
  gemm_bias_kernel<bf16, 1><<<dim3(64, 8), 256, 0, stream>>>(X, Tk, bk, Kc);
  cvt_kernel<<<dim3(4096), 256, 0, stream>>>(iv, X);
  gemm_bias_kernel<bf16, 1><<<dim3(64, 8), 256, 0, stream>>>(X, Tv, bv, Vc);
  transpose_v_kernel<<<dim3(32, 64), 256, 0, stream>>>(Vc, Vtp);
  attention_kernel<<<dim3(8, 16, 4), 256, 0, stream>>>(Qc, Kc, Vtp, Cx);
  gemm_bias_kernel<float, 0><<<dim3(64, 8), 256, 0, stream>>>(Cx, To, bo,
                                                              (float*)d_out);
}